// Round 1
// 445.103 us; speedup vs baseline: 1.0336x; 1.0336x over previous
//
#include <hip/hip_runtime.h>
#include <hip/hip_bf16.h>
#include <math.h>

#define D_MODEL   1024
#define D_STATE   128
#define HEADDIM   64
#define CHUNK     64
#define D_INNER   2048
#define NHEADS    32
#define D_IN_PROJ 4384   // 2*2048 + 2*128 + 32
#define CONV_CH   2304   // 2048 + 256
#define RCOLS     2336   // CONV_CH + NHEADS (xBC-raw + dt-raw columns)
#define WINT_ROWS 4480   // D_IN_PROJ padded so col-tile 34 stays in-bounds
#define BATCH     2
#define SEQ       4096
#define NCHUNK    64     // SEQ / CHUNK
#define ROWS      (BATCH*SEQ)   // 8192
#define EPS_RMS   1e-5f

typedef __hip_bfloat16 bf16;
typedef __bf16 bf16x8_t __attribute__((ext_vector_type(8)));
typedef float  f32x4_t  __attribute__((ext_vector_type(4)));

__device__ __forceinline__ float siluf_(float x){ return x/(1.f+expf(-x)); }
__device__ __forceinline__ float ldf(const float* p){ return *p; }
__device__ __forceinline__ float ldf(const bf16* p){ return __bfloat162float(*p); }
__device__ __forceinline__ void  stf(float* p, float v){ *p = v; }
__device__ __forceinline__ void  stf(bf16* p, float v){ *p = __float2bfloat16(v); }

__device__ __forceinline__ __bf16 tobf(float v){
    __hip_bfloat16 t = __float2bfloat16(v);
    return *reinterpret_cast<__bf16*>(&t);
}
__device__ __forceinline__ unsigned short bfbits(float v){
    __hip_bfloat16 t = __float2bfloat16(v);
    return *reinterpret_cast<unsigned short*>(&t);
}
__device__ __forceinline__ float bfbits2f(unsigned short u){
    union { unsigned u; float f; } cv; cv.u = ((unsigned)u) << 16; return cv.f;
}

// async global->LDS, 16 B per lane; LDS dest is wave-uniform base + lane*16.
__device__ __forceinline__ void async16(const void* g, void* l) {
    __builtin_amdgcn_global_load_lds(
        (const __attribute__((address_space(1))) unsigned int*)g,
        (__attribute__((address_space(3))) unsigned int*)l, 16, 0, 0);
}

// ---------------------------------------------------------------------------
// Pipelined MFMA core: 256x128 tile, BK=64, 8 waves (512 thr), 3-deep LDS
// ring buffer (prefetch distance 2), counted s_waitcnt vmcnt(6) -- never
// drained to 0 in the main loop (T3+T4).  LDS XOR-swizzled (byte ^=
// (row&7)<<4) with the inverse swizzle pre-applied to the per-lane GLOBAL
// source address so global_load_lds keeps a linear LDS dest (rule #21).
// Wave (wm=wid>>1, wn=wid&1) owns a 64x64 output patch = 4x4 MFMA frags.
//   a/b frag: lane row=lane&15, k=ks*32+quad*8+j ; D: col=lane&15,
//   row=quad*4+reg.
// LDS: As = 3 * 256*64 bf16 (96 KiB), Bs = 3 * 128*64 bf16 (48 KiB).
// ---------------------------------------------------------------------------
struct Core {
    f32x4_t acc[4][4];

    __device__ __forceinline__ void stageA(const bf16* __restrict__ A, int lda,
                                           int row0, int kk, __bf16* Asb,
                                           int tid, int lcb, int wb) {
#pragma unroll
        for (int c = 0; c < 4; ++c) {
            const char* src = (const char*)(A + (size_t)(row0 + c * 64 + (tid >> 3)) * lda + kk) + lcb;
            async16(src, Asb + c * 4096 + wb);
        }
    }
    __device__ __forceinline__ void stageB(const bf16* __restrict__ Bt, int ldb,
                                           int col0, int kk, __bf16* Bsb,
                                           int tid, int lcb, int wb) {
#pragma unroll
        for (int c = 0; c < 2; ++c) {
            const char* src = (const char*)(Bt + (size_t)(col0 + c * 64 + (tid >> 3)) * ldb + kk) + lcb;
            async16(src, Bsb + c * 4096 + wb);
        }
    }

    __device__ __forceinline__ void run(const bf16* __restrict__ A,
                                        const bf16* __restrict__ Bt,
                                        int lda, int ldb,
                                        int row0, int col0, int k0, int nt,
                                        __bf16* As, __bf16* Bs, int tid) {
        const int wave = tid >> 6, lane = tid & 63;
        const int quad = lane >> 4, l16 = lane & 15;
        const int wm = wave >> 1, wn = wave & 1;
        const int wb  = wave << 9;                       // wave*512 elements
        // inverse-swizzled source column-byte for staging (constant per thread)
        const int lcb = (((tid & 7) ^ ((tid >> 3) & 7)) << 4);
        // read-side swizzle xor (row&7 == l16&7 for all frag reads)
        const int xb = (l16 & 7) << 4;

#pragma unroll
        for (int i = 0; i < 4; ++i)
#pragma unroll
            for (int j = 0; j < 4; ++j) acc[i][j] = (f32x4_t){0.f, 0.f, 0.f, 0.f};

        int aoff[4][2], boff[4][2];
#pragma unroll
        for (int mi = 0; mi < 4; ++mi)
#pragma unroll
            for (int ks = 0; ks < 2; ++ks) {
                const int cb = ((ks << 6) | (quad << 4)) ^ xb;
                aoff[mi][ks] = (wm * 64 + mi * 16 + l16) * 128 + cb;
                boff[mi][ks] = (wn * 64 + mi * 16 + l16) * 128 + cb;
            }

        // prologue: prime tiles 0 and 1 (12 loads/thread in flight)
        stageA(A, lda, row0, k0,      As,          tid, lcb, wb);
        stageB(Bt, ldb, col0, k0,     Bs,          tid, lcb, wb);
        stageA(A, lda, row0, k0 + 64, As + 16384,  tid, lcb, wb);
        stageB(Bt, ldb, col0, k0 + 64, Bs + 8192,  tid, lcb, wb);

        const char* AsC = (const char*)As;
        const char* BsC = (const char*)Bs;
        int cur = 0, sb = 2;
        for (int t = 0; t < nt; ++t) {
            // tile t's 6 loads are the oldest; allow tile t+1's 6 to fly.
            if (t < nt - 1) asm volatile("s_waitcnt vmcnt(6)" ::: "memory");
            else            asm volatile("s_waitcnt vmcnt(0)" ::: "memory");
            __builtin_amdgcn_s_barrier();
            asm volatile("" ::: "memory");
            if (t + 2 < nt) {   // prefetch distance 2 into the free ring slot
                stageA(A, lda, row0, k0 + (t + 2) * 64, As + sb * 16384, tid, lcb, wb);
                stageB(Bt, ldb, col0, k0 + (t + 2) * 64, Bs + sb * 8192, tid, lcb, wb);
            }
            const char* Ab = AsC + cur * 32768;
            const char* Bb = BsC + cur * 16384;
            bf16x8_t af[4][2], bfr[4][2];
#pragma unroll
            for (int mi = 0; mi < 4; ++mi)
#pragma unroll
                for (int ks = 0; ks < 2; ++ks) {
                    af[mi][ks]  = *(const bf16x8_t*)(Ab + aoff[mi][ks]);
                    bfr[mi][ks] = *(const bf16x8_t*)(Bb + boff[mi][ks]);
                }
            __builtin_amdgcn_s_setprio(1);
#pragma unroll
            for (int ks = 0; ks < 2; ++ks)
#pragma unroll
                for (int mi = 0; mi < 4; ++mi)
#pragma unroll
                    for (int ni = 0; ni < 4; ++ni)
                        acc[mi][ni] = __builtin_amdgcn_mfma_f32_16x16x32_bf16(
                            af[mi][ks], bfr[ni][ks], acc[mi][ni], 0, 0, 0);
            __builtin_amdgcn_s_setprio(0);
            cur = (cur + 1 == 3) ? 0 : cur + 1;
            sb  = (sb  + 1 == 3) ? 0 : sb  + 1;
        }
    }
};

// Fused Z|R GEMM: grid (32 row-tiles of 256, 35 col-tiles of 128).
__global__ __launch_bounds__(512) void gemm_zr_fused(const bf16* __restrict__ A,
                                                     const bf16* __restrict__ Bt,
                                                     bf16* __restrict__ Z,
                                                     bf16* __restrict__ R) {
    __shared__ __align__(16) __bf16 As[3 * 16384];   // 96 KiB
    __shared__ __align__(16) __bf16 Bs[3 * 8192];    // 48 KiB
    const int tid = threadIdx.x;
    const int row0 = blockIdx.x * 256;
    const int ct   = blockIdx.y;
    Core g;
    g.run(A, Bt, D_MODEL, D_MODEL, row0, ct * 128, 0, 16, As, Bs, tid);

    const int wave = tid >> 6, lane = tid & 63;
    const int quad = lane >> 4, l16 = lane & 15;
    const int wm = wave >> 1, wn = wave & 1;
    bf16* Cp; int ldc_, cl0, ncols;
    if (ct < 16) { Cp = Z; ldc_ = D_INNER; cl0 = ct * 128;           ncols = D_INNER; }
    else         { Cp = R; ldc_ = RCOLS;   cl0 = ct * 128 - D_INNER; ncols = RCOLS; }
#pragma unroll
    for (int ni = 0; ni < 4; ++ni) {
        int gc = cl0 + wn * 64 + ni * 16 + l16;
        if (gc >= ncols) continue;
#pragma unroll
        for (int mi = 0; mi < 4; ++mi)
#pragma unroll
            for (int r = 0; r < 4; ++r) {
                int gr = row0 + wm * 64 + mi * 16 + quad * 4 + r;
                stf(&Cp[(size_t)gr * ldc_ + gc], g.acc[mi][ni][r]);
            }
    }
}

// Out GEMM, full K=2048, fp32 direct to out. grid (32, 8) = 256 blocks (1/CU).
__global__ __launch_bounds__(512) void gemm_out_kernel(const bf16* __restrict__ A,
                                                       const bf16* __restrict__ Bt,
                                                       float* __restrict__ out) {
    __shared__ __align__(16) __bf16 As[3 * 16384];
    __shared__ __align__(16) __bf16 Bs[3 * 8192];
    const int tid = threadIdx.x;
    const int row0 = blockIdx.x * 256;
    const int col0 = blockIdx.y * 128;
    Core g;
    g.run(A, Bt, D_INNER, D_INNER, row0, col0, 0, 32, As, Bs, tid);

    const int wave = tid >> 6, lane = tid & 63;
    const int quad = lane >> 4, l16 = lane & 15;
    const int wm = wave >> 1, wn = wave & 1;
#pragma unroll
    for (int ni = 0; ni < 4; ++ni) {
        int gc = col0 + wn * 64 + ni * 16 + l16;
#pragma unroll
        for (int mi = 0; mi < 4; ++mi)
#pragma unroll
            for (int r = 0; r < 4; ++r) {
                int gr = row0 + wm * 64 + mi * 16 + quad * 4 + r;
                out[(size_t)gr * D_MODEL + gc] = g.acc[mi][ni][r];
            }
    }
}

// fp32 -> bf16 cast, 4 elems/thread
__global__ void cvt_bf16_kernel(const float* __restrict__ src,
                                bf16* __restrict__ dst, int n4) {
    int i = blockIdx.x * 256 + threadIdx.x;
    if (i >= n4) return;
    float4 v = ((const float4*)src)[i];
    dst[i * 4 + 0] = __float2bfloat16(v.x);
    dst[i * 4 + 1] = __float2bfloat16(v.y);
    dst[i * 4 + 2] = __float2bfloat16(v.z);
    dst[i * 4 + 3] = __float2bfloat16(v.w);
}

// Wt[c][r] = W[r][c], fp32 -> bf16.
__global__ __launch_bounds__(256) void transpose_cvt_kernel(const float* __restrict__ W,
                                                            bf16* __restrict__ Wt,
                                                            int R, int C, int Cpad) {
    __shared__ float tile[32][33];
    int c0 = blockIdx.x * 32, r0 = blockIdx.y * 32;
    int tx = threadIdx.x & 31, ty = threadIdx.x >> 5;
    for (int i = ty; i < 32; i += 8) {
        int r = r0 + i, c = c0 + tx;
        tile[i][tx] = (c < C) ? W[(size_t)r * C + c] : 0.f;
    }
    __syncthreads();
    for (int i = ty; i < 32; i += 8) {
        int c = c0 + i, r = r0 + tx;
        stf(&Wt[(size_t)c * R + r], tile[tx][i]);
    }
}

// conv_w[ch][k] fp32  ->  Wc[k][ch] bf16  (coalesced tap-major layout)
__global__ void prep_convw_kernel(const float* __restrict__ conv_w,
                                  bf16* __restrict__ Wc) {
    int i = blockIdx.x * 256 + threadIdx.x;     // CONV_CH*4 = 9216
    if (i >= CONV_CH * 4) return;
    int ch = i >> 2, k = i & 3;
    Wc[k * CONV_CH + ch] = __float2bfloat16(conv_w[ch * 4 + k]);
}

// ---------------------------------------------------------------------------
// Depthwise causal conv (k=4) + bias + SiLU.  One thread = 4 rows x 8 channels.
// ---------------------------------------------------------------------------
__global__ __launch_bounds__(256) void conv_silu_kernel(const bf16* __restrict__ R,
                                                        const bf16* __restrict__ Wc,
                                                        const float* __restrict__ conv_b,
                                                        bf16* __restrict__ xBC) {
    int idx = blockIdx.x * 256 + threadIdx.x;   // ROWS/4 * 288 exactly
    int rq = idx / 288;
    int g = idx - rq * 288;
    int ch0 = g * 8;
    int row0 = rq * 4;
    int l0 = row0 & (SEQ - 1);

    uint4 rv[7];
#pragma unroll
    for (int j = 0; j < 7; ++j) {
        int ls = l0 - 3 + j;
        rv[j] = (ls >= 0) ? *(const uint4*)&R[(size_t)(row0 - 3 + j) * RCOLS + ch0]
                          : make_uint4(0u, 0u, 0u, 0u);
    }
    uint4 wv[4];
#pragma unroll
    for (int k = 0; k < 4; ++k)
        wv[k] = *(const uint4*)&Wc[k * CONV_CH + ch0];
    float4 b0 = ((const float4*)conv_b)[ch0 / 4];
    float4 b1 = ((const float4*)conv_b)[ch0 / 4 + 1];
    const float bias[8] = {b0.x, b0.y, b0.z, b0.w, b1.x, b1.y, b1.z, b1.w};
    float wf[4][8];
#pragma unroll
    for (int k = 0; k < 4; ++k) {
        const unsigned* wp = (const unsigned*)&wv[k];
#pragma unroll
        for (int j2 = 0; j2 < 4; ++j2) {
            wf[k][2 * j2]     = bfbits2f((unsigned short)(wp[j2] & 0xffff));
            wf[k][2 * j2 + 1] = bfbits2f((unsigned short)(wp[j2] >> 16));
        }
    }
#pragma unroll
    for (int j = 0; j < 4; ++j) {
        float acc[8];
#pragma unroll
        for (int cc = 0; cc < 8; ++cc) acc[cc] = bias[cc];
#pragma unroll
        for (int k = 0; k < 4; ++k) {
            const unsigned* vp = (const unsigned*)&rv[j + k];
#pragma unroll
            for (int j2 = 0; j2 < 4; ++j2) {
                unsigned v = vp[j2];
                acc[2 * j2]     += wf[k][2 * j2]     * bfbits2f((unsigned short)(v & 0xffff));
                acc[2 * j2 + 1] += wf[k][2 * j2 + 1] * bfbits2f((unsigned short)(v >> 16));
            }
        }
        unsigned o[4];
#pragma unroll
        for (int j2 = 0; j2 < 4; ++j2)
            o[j2] = (unsigned)bfbits(siluf_(acc[2 * j2])) |
                    ((unsigned)bfbits(siluf_(acc[2 * j2 + 1])) << 16);
        *(uint4*)&xBC[(size_t)(row0 + j) * CONV_CH + ch0] = make_uint4(o[0], o[1], o[2], o[3]);
    }
}

// dt[row][h0..h0+7] = softplus(R[row][CONV_CH+h] + dt_bias[h]), vectorized.
__global__ void dt_kernel(const bf16* __restrict__ R,
                          const float* __restrict__ dt_bias,
                          float* __restrict__ dtb) {
    int i = blockIdx.x * 256 + threadIdx.x;         // ROWS*4 exactly
    int row = i >> 2, h0 = (i & 3) * 8;
    uint4 v = *(const uint4*)&R[(size_t)row * RCOLS + CONV_CH + h0];
    float4 bia0 = ((const float4*)dt_bias)[h0 / 4];
    float4 bia1 = ((const float4*)dt_bias)[h0 / 4 + 1];
    const unsigned vv[4] = {v.x, v.y, v.z, v.w};
    const float bb[8] = {bia0.x, bia0.y, bia0.z, bia0.w, bia1.x, bia1.y, bia1.z, bia1.w};
    float o[8];
#pragma unroll
    for (int j = 0; j < 4; ++j) {
        float a = bfbits2f((unsigned short)(vv[j] & 0xffff)) + bb[2*j];
        float c = bfbits2f((unsigned short)(vv[j] >> 16)) + bb[2*j+1];
        o[2*j]   = (a > 20.f) ? a : log1pf(expf(a));
        o[2*j+1] = (c > 20.f) ? c : log1pf(expf(c));
    }
    float* dp = &dtb[(size_t)row * NHEADS + h0];
    *(float4*)dp       = make_float4(o[0], o[1], o[2], o[3]);
    *(float4*)(dp + 4) = make_float4(o[4], o[5], o[6], o[7]);
}

// Per (b,c,h): inclusive cumsum of A[h]*dt over the 64-long chunk.
__global__ void acum_kernel(const float* __restrict__ dtb,
                            const float* __restrict__ A_log,
                            float* __restrict__ Acum) {
    int bch = blockIdx.x;
    int h = bch & 31;
    int bc = bch >> 5;
    int c = bc & 63, b = bc >> 6;
    int row0 = b * SEQ + c * CHUNK;
    __shared__ float sh[64];
    int l = threadIdx.x;
    float Ah = -expf(A_log[h]);
    sh[l] = Ah * dtb[(size_t)(row0 + l) * NHEADS + h];
    __syncthreads();
    float s = 0.f;
    for (int j = 0; j <= l; ++j) s += sh[j];
    Acum[(size_t)bch * 64 + l] = s;
}

// ---------------------------------------------------------------------------
// MFMA G-chunk: G[l][s] = sum_n C[l,n]*B[s,n].  One wave per (b,c).
// ---------------------------------------------------------------------------
__global__ __launch_bounds__(64) void gchunk_mfma_kernel(const bf16* __restrict__ xBC,
                                                         float* __restrict__ Gbuf) {
    int bc = blockIdx.x;
    int c = bc & 63, b = bc >> 6;
    int row0 = b * SEQ + c * CHUNK;
    int lane = threadIdx.x;
    int quad = lane >> 4, l16 = lane & 15;

    f32x4_t acc[4][4];
#pragma unroll
    for (int i = 0; i < 4; ++i)
#pragma unroll
        for (int j = 0; j < 4; ++j) acc[i][j] = (f32x4_t){0.f, 0.f, 0.f, 0.f};

#pragma unroll
    for (int ks = 0; ks < 4; ++ks) {
        bf16x8_t a[4], bb[4];
#pragma unroll
        for (int mi = 0; mi < 4; ++mi)
            a[mi] = *(const bf16x8_t*)&xBC[(size_t)(row0 + mi * 16 + l16) * CONV_CH +
                                           D_INNER + D_STATE + ks * 32 + quad * 8];
#pragma unroll
        for (int ni = 0; ni < 4; ++ni)
            bb[ni] = *(const bf16x8_t*)&xBC[(size_t)(row0 + ni * 16 + l16) * CONV_CH +
                                            D_INNER + ks * 32 + quad * 8];
#pragma unroll
        for (int mi = 0; mi < 4; ++mi)
#pragma unroll
            for (int ni = 0; ni < 4; ++ni)
                acc[mi][ni] = __builtin_amdgcn_mfma_f32_16x16x32_bf16(
                    a[mi], bb[ni], acc[mi][ni], 0, 0, 0);
    }
#pragma unroll
    for (int ni = 0; ni < 4; ++ni) {
        int s = ni * 16 + l16;
#pragma unroll
        for (int mi = 0; mi < 4; ++mi)
#pragma unroll
            for (int r = 0; r < 4; ++r) {
                int l = mi * 16 + quad * 4 + r;
                Gbuf[(size_t)bc * 4096 + l * 64 + s] = acc[mi][ni][r];
            }
    }
}

// ---------------------------------------------------------------------------
// MFMA chunk-states: S[p][n] = sum_l (x[l,p]*dt[l]*dec[l]) * B[l,n].
// ---------------------------------------------------------------------------
__global__ __launch_bounds__(256) void states_mfma_kernel(const bf16* __restrict__ xBC,
                                                          const float* __restrict__ dtb,
                                                          const float* __restrict__ Acum,
                                                          bf16* __restrict__ states) {
    __shared__ __align__(16) __bf16 BsT[128 * 72];      // [n][l], stride 72 (144 B)
    __shared__ __align__(16) __bf16 xdT[4][64 * 72];    // per-wave [p][l]
    __shared__ float dtdec[4][64];
    int bcq = blockIdx.x;                 // (b*64+c)*8 + hq
    int hq = bcq & 7, bc = bcq >> 3;
    int c = bc & 63, b = bc >> 6;
    int tid = threadIdx.x, wave = tid >> 6, lane = tid & 63;
    int h = hq * 4 + wave;
    int bch = bc * 32 + h;
    int row0 = b * SEQ + c * CHUNK;
    int quad = lane >> 4, l16 = lane & 15;

    {
        float alast = Acum[(size_t)bch * 64 + 63];
        float a = Acum[(size_t)bch * 64 + lane];
        dtdec[wave][lane] = dtb[(size_t)(row0 + lane) * NHEADS + h] * expf(alast - a);
    }
    __syncthreads();
    for (int it = 0; it < 16; ++it) {
        int i2 = tid + 256 * it;
        int l = i2 >> 6;
        int n0 = (i2 & 63) * 2;
        unsigned v = *(const unsigned*)&xBC[(size_t)(row0 + l) * CONV_CH + D_INNER + n0];
        *(unsigned short*)&BsT[(n0    ) * 72 + l] = (unsigned short)(v & 0xffff);
        *(unsigned short*)&BsT[(n0 + 1) * 72 + l] = (unsigned short)(v >> 16);
    }
    for (int it = 0; it < 32; ++it) {
        int l = 2 * it + (lane >> 5);
        int p0 = (lane & 31) * 2;
        unsigned v = *(const unsigned*)&xBC[(size_t)(row0 + l) * CONV_CH + h * 64 + p0];
        float f = dtdec[wave][l];
        xdT[wave][(p0    ) * 72 + l] = tobf(bfbits2f((unsigned short)(v & 0xffff)) * f);
        xdT[wave][(p0 + 1) * 72 + l] = tobf(bfbits2f((unsigned short)(v >> 16)) * f);
    }
    __syncthreads();

    f32x4_t acc[4][8];
#pragma unroll
    for (int i = 0; i < 4; ++i)
#pragma unroll
        for (int j = 0; j < 8; ++j) acc[i][j] = (f32x4_t){0.f, 0.f, 0.f, 0.f};
#pragma unroll
    for (int ks = 0; ks < 2; ++ks) {
        bf16x8_t a[4], bb[8];
#pragma unroll
        for (int mi = 0; mi < 4; ++mi)
            a[mi] = *(const bf16x8_t*)(&xdT[wave][(mi * 16 + l16) * 72 + ks * 32 + quad * 8]);
#pragma unroll
        for (int ni = 0; ni < 8; ++ni)
            bb[ni] = *(const bf16x8_t*)(&BsT[(ni * 16 + l16) * 72 + ks * 32 + quad * 8]);
#pragma unroll
        for (int mi = 0; mi < 4; ++mi)
#pragma unroll
            for (int ni = 0; ni < 8; ++ni)
                acc[mi][ni] = __builtin_amdgcn_mfma_f32_16x16x32_bf16(
                    a[mi], bb[ni], acc[mi][ni], 0, 0, 0);
    }
#pragma unroll
    for (int ni = 0; ni < 8; ++ni) {
        int n = ni * 16 + l16;
#pragma unroll
        for (int mi = 0; mi < 4; ++mi)
#pragma unroll
            for (int r = 0; r < 4; ++r) {
                int p = mi * 16 + quad * 4 + r;
                stf(&states[(size_t)bch * 8192 + p * 128 + n], acc[mi][ni][r]);
            }
    }
}

// Inter-chunk scan (in place), 4 states/thread, fp32 carry.
__global__ void scan_kernel(const float* __restrict__ Acum,
                            bf16* __restrict__ states) {
    int i = blockIdx.x * 256 + threadIdx.x;     // BATCH*NHEADS*2048 exactly
    int pn0 = (i & 2047) * 4;
    int bh = i >> 11;
    int h = bh & 31, b = bh >> 5;
    float carry[4] = {0.f, 0.f, 0.f, 0.f};
    for (int c = 0; c < NCHUNK; ++c) {
        int bch = (b * NCHUNK + c) * NHEADS + h;
        bf16* sp = &states[(size_t)bch * 8192 + pn0];
        uint2 v = *(const uint2*)sp;
        float s0 = bfbits2f((unsigned short)(v.x & 0xffff));
        float s1 = bfbits2f((unsigned short)(v.x >> 16));
        float s2 = bfbits2f((unsigned short)(v.y & 0xffff));
        float s3 = bfbits2f((unsigned short)(v.y >> 16));
        uint2 o;
        o.x = (unsigned)bfbits(carry[0]) | ((unsigned)bfbits(carry[1]) << 16);
        o.y = (unsigned)bfbits(carry[2]) | ((unsigned)bfbits(carry[3]) << 16);
        *(uint2*)sp = o;
        float dec = expf(Acum[(size_t)bch * 64 + 63]);
        carry[0] = carry[0] * dec + s0;
        carry[1] = carry[1] * dec + s1;
        carry[2] = carry[2] * dec + s2;
        carry[3] = carry[3] * dec + s3;
    }
}

// ---------------------------------------------------------------------------
// MFMA Y: Y[l][p] = sum_s M[l][s]*x[s][p] + sum_n (C[l][n]*sdo[l])*state[p][n]
//                  + D[h]*x[l][p].   One wave per (b,c,h).
// ---------------------------------------------------------------------------
__global__ __launch_bounds__(64) void y_mfma_kernel(const bf16* __restrict__ xBC,
                                                    const float* __restrict__ dtb,
                                                    const float* __restrict__ Acum,
                                                    const float* __restrict__ Gbuf,
                                                    const bf16* __restrict__ states,
                                                    const float* __restrict__ Dv,
                                                    bf16* __restrict__ y) {
    __shared__ __align__(16) __bf16 Mm[64 * 72];
    __shared__ __align__(16) __bf16 xsT[64 * 72];
    __shared__ float acs[64], dtss[64], sdos[64];
    int bch = blockIdx.x;
    int h = bch & 31, bc = bch >> 5;
    int c = bc & 63, b = bc >> 6;
    int row0 = b * SEQ + c * CHUNK;
    int lane = threadIdx.x;
    int quad = lane >> 4, l16 = lane & 15;

    {
        float a = Acum[(size_t)bch * 64 + lane];
        acs[lane] = a;
        sdos[lane] = expf(a);
        dtss[lane] = dtb[(size_t)(row0 + lane) * NHEADS + h];
    }
    __syncthreads();
    for (int l = 0; l < 64; ++l) {
        int s = lane;
        float d = acs[l] - acs[s];
        float g = (s <= l) ? Gbuf[(size_t)bc * 4096 + l * 64 + s] * dtss[s] : 0.f;
        float coef = g * expf((s <= l) ? d : 0.f);
        Mm[l * 72 + s] = tobf(coef);
    }
    for (int it = 0; it < 32; ++it) {
        int l = 2 * it + (lane >> 5);
        int p0 = (lane & 31) * 2;
        unsigned v = *(const unsigned*)&xBC[(size_t)(row0 + l) * CONV_CH + h * 64 + p0];
        *(unsigned short*)&xsT[(p0    ) * 72 + l] = (unsigned short)(v & 0xffff);
        *(unsigned short*)&xsT[(p0 + 1) * 72 + l] = (unsigned short)(v >> 16);
    }
    __syncthreads();

    f32x4_t acc[4][4];
#pragma unroll
    for (int i = 0; i < 4; ++i)
#pragma unroll
        for (int j = 0; j < 4; ++j) acc[i][j] = (f32x4_t){0.f, 0.f, 0.f, 0.f};

#pragma unroll
    for (int ks = 0; ks < 2; ++ks) {
        bf16x8_t a[4], bb[4];
#pragma unroll
        for (int mi = 0; mi < 4; ++mi)
            a[mi] = *(const bf16x8_t*)(&Mm[(mi * 16 + l16) * 72 + ks * 32 + quad * 8]);
#pragma unroll
        for (int ni = 0; ni < 4; ++ni)
            bb[ni] = *(const bf16x8_t*)(&xsT[(ni * 16 + l16) * 72 + ks * 32 + quad * 8]);
#pragma unroll
        for (int mi = 0; mi < 4; ++mi)
#pragma unroll
            for (int ni = 0; ni < 4; ++ni)
                acc[mi][ni] = __builtin_amdgcn_mfma_f32_16x16x32_bf16(
                    a[mi], bb[ni], acc[mi][ni], 0, 0, 0);
    }
    float sdo_mi[4];
#pragma unroll
    for (int mi = 0; mi < 4; ++mi) sdo_mi[mi] = sdos[mi * 16 + l16];
#pragma unroll
    for (int ks = 0; ks < 4; ++ks) {
        bf16x8_t a[4], bb[4];
#pragma unroll
        for (int mi = 0; mi < 4; ++mi) {
            const unsigned* cp = (const unsigned*)&xBC[(size_t)(row0 + mi * 16 + l16) * CONV_CH
                                                       + D_INNER + D_STATE + ks * 32 + quad * 8];
            float sc = sdo_mi[mi];
#pragma unroll
            for (int jj = 0; jj < 4; ++jj) {
                unsigned v = cp[jj];
                a[mi][2 * jj    ] = tobf(bfbits2f((unsigned short)(v & 0xffff)) * sc);
                a[mi][2 * jj + 1] = tobf(bfbits2f((unsigned short)(v >> 16)) * sc);
            }
        }
#pragma unroll
        for (int ni = 0; ni < 4; ++ni)
            bb[ni] = *(const bf16x8_t*)&states[(size_t)bch * 8192 + (ni * 16 + l16) * 128
                                               + ks * 32 + quad * 8];
#pragma unroll
        for (int mi = 0; mi < 4; ++mi)
#pragma unroll
            for (int ni = 0; ni < 4; ++ni)
                acc[mi][ni] = __builtin_amdgcn_mfma_f32_16x16x32_bf16(
                    a[mi], bb[ni], acc[mi][ni], 0, 0, 0);
    }
    float Dh = Dv[h];
#pragma unroll
    for (int ni = 0; ni < 4; ++ni) {
        int p = ni * 16 + l16;
#pragma unroll
        for (int mi = 0; mi < 4; ++mi)
#pragma unroll
            for (int r = 0; r < 4; ++r) {
                int l = mi * 16 + quad * 4 + r;
                float xv = bfbits2f(*(const unsigned short*)&xsT[p * 72 + l]);
                stf(&y[(size_t)(row0 + l) * D_INNER + h * 64 + p],
                    acc[mi][ni][r] + Dh * xv);
            }
    }
}

// Per row: v = y * silu(z); y = v * rsqrt(mean(v^2)+eps) * norm_w.
__global__ __launch_bounds__(256) void gate_norm_kernel(const bf16* __restrict__ Z,
                                                        const float* __restrict__ nw,
                                                        bf16* __restrict__ y) {
    int row = blockIdx.x;
    int tid = threadIdx.x;
    int col0 = tid * 8;
    uint4 zv = *(const uint4*)&Z[(size_t)row * D_INNER + col0];
    uint4 yv = *(const uint4*)&y[(size_t)row * D_INNER + col0];
    const unsigned zz[4] = {zv.x, zv.y, zv.z, zv.w};
    const unsigned yy[4] = {yv.x, yv.y, yv.z, yv.w};
    float vals[8];
    float local = 0.f;
#pragma unroll
    for (int j = 0; j < 4; ++j) {
        float z0 = bfbits2f((unsigned short)(zz[j] & 0xffff));
        float z1 = bfbits2f((unsigned short)(zz[j] >> 16));
        float y0 = bfbits2f((unsigned short)(yy[j] & 0xffff));
        float y1 = bfbits2f((unsigned short)(yy[j] >> 16));
        float v0 = y0 * siluf_(z0);
        float v1 = y1 * siluf_(z1);
        vals[2*j] = v0; vals[2*j+1] = v1;
        local += v0 * v0 + v1 * v1;
    }
#pragma unroll
    for (int off = 32; off; off >>= 1) local += __shfl_down(local, off, 64);
    __shared__ float wsum[4];
    if ((tid & 63) == 0) wsum[tid >> 6] = local;
    __syncthreads();
    float total = wsum[0] + wsum[1] + wsum[2] + wsum[3];
    float scale = rsqrtf(total / (float)D_INNER + EPS_RMS);
    float4 w0 = ((const float4*)nw)[col0 / 4];
    float4 w1 = ((const float4*)nw)[col0 / 4 + 1];
    const float ww[8] = {w0.x, w0.y, w0.z, w0.w, w1.x, w1.y, w1.z, w1.w};
    unsigned o[4];
#pragma unroll
    for (int j = 0; j < 4; ++j)
        o[j] = (unsigned)bfbits(vals[2*j] * scale * ww[2*j]) |
               ((unsigned)bfbits(vals[2*j+1] * scale * ww[2*j+1]) << 16);
    *(uint4*)&y[(size_t)row * D_INNER + col0] = make_uint4(o[0], o[1], o[2], o[3]);
}

// ---------------------------------------------------------------------------
extern "C" void kernel_launch(void* const* d_in, const int* in_sizes, int n_in,
                              void* d_out, int out_size, void* d_ws, size_t ws_size,
                              hipStream_t stream) {
    const float* u       = (const float*)d_in[0];
    const float* W_in    = (const float*)d_in[1];
    const float* conv_w  = (const float*)d_in[2];
    const float* conv_b  = (const float*)d_in[3];
    const float* dt_bias = (const float*)d_in[4];
    const float* A_log   = (const float*)d_in[5];
    const float* Dv      = (const float*)d_in[6];
    const float* norm_w  = (const float*)d_in[7];
    const float* W_out   = (const float*)d_in[8];
    float* out = (float*)d_out;

    const size_t sz_xBC    = (size_t)ROWS * CONV_CH * 2;
    const size_t sz_Z      = (size_t)ROWS * D_INNER * 2;
    const size_t sz_y      = (size_t)ROWS * D_INNER * 2;
    const size_t sz_states = (size_t)BATCH * NCHUNK * NHEADS * 8192 * 2;  // 67.1 MB
    const size_t sz_dtb    = (size_t)ROWS * NHEADS * 4;
    const size_t sz_Acum   = (size_t)BATCH * NCHUNK * NHEADS * 64 * 4;
    const size_t sz_Gbuf   = (size_t)BATCH * NCHUNK * 4096 * 4;
    const size_t sz_WinT   = (size_t)WINT_ROWS * D_MODEL * 2;
    const size_t sz_WoutT  = (size_t)D_MODEL * D_INNER * 2;
    const size_t sz_Wc     = (size_t)CONV_CH * 4 * 2;
    const size_t need = sz_xBC + sz_Z + sz_y + sz_states + sz_dtb + sz_Acum +
                        sz_Gbuf + sz_WinT + sz_WoutT + sz_Wc;
    if (ws_size < need) {
        hipMemsetAsync(d_out, 0, (size_t)out_size * sizeof(float), stream);
        return;
    }
    char* ws = (char*)d_ws;
    size_t off = 0;
    bf16*  xBC    = (bf16*) (ws + off); off += sz_xBC;
    bf16*  Z      = (bf16*) (ws + off); off += sz_Z;
    bf16*  y      = (bf16*) (ws + off); off += sz_y;
    bf16*  states = (bf16*) (ws + off); off += sz_states;
    float* dtb    = (float*)(ws + off); off += sz_dtb;
    float* Acum   = (float*)(ws + off); off += sz_Acum;
    float* Gbuf   = (float*)(ws + off); off += sz_Gbuf;
    bf16*  W_inT  = (bf16*) (ws + off); off += sz_WinT;
    bf16*  W_outT = (bf16*) (ws + off); off += sz_WoutT;
    bf16*  Wc     = (bf16*) (ws + off); off += sz_Wc;
    // Aliases of the states region (67.1 MB), dead before their overwrite:
    //  - R (38.3 MB) + u_bf16 (16.8 MB): dead before states_mfma_kernel.
    bf16*  R        = states;
    bf16*  u_bf16   = (bf16*)((char*)states + (size_t)ROWS * RCOLS * 2);

    // 0) prep
    cvt_bf16_kernel<<<(ROWS * D_MODEL / 4 + 255) / 256, 256, 0, stream>>>(
        u, u_bf16, ROWS * D_MODEL / 4);
    transpose_cvt_kernel<<<dim3(WINT_ROWS / 32, D_MODEL / 32), 256, 0, stream>>>(
        W_in, W_inT, D_MODEL, D_IN_PROJ, WINT_ROWS);
    transpose_cvt_kernel<<<dim3(D_MODEL / 32, D_INNER / 32), 256, 0, stream>>>(
        W_out, W_outT, D_INNER, D_MODEL, D_MODEL);
    prep_convw_kernel<<<(CONV_CH * 4 + 255) / 256, 256, 0, stream>>>(conv_w, Wc);
    // 1) fused Z|R GEMM: pipelined 256x128 core, 32x35 = 1120 blocks
    gemm_zr_fused<<<dim3(ROWS / 256, 35), 512, 0, stream>>>(u_bf16, W_inT, Z, R);
    // 2) conv + silu (4 rows/thread) ; dt
    conv_silu_kernel<<<ROWS / 4 * 288 / 256, 256, 0, stream>>>(R, Wc, conv_b, xBC);
    dt_kernel<<<ROWS * 4 / 256, 256, 0, stream>>>(R, dt_bias, dtb);
    // 3) per-chunk cumsum of A*dt
    acum_kernel<<<BATCH * NCHUNK * NHEADS, 64, 0, stream>>>(dtb, A_log, Acum);
    // 4) G = C @ B^T per (b,c)  (MFMA)
    gchunk_mfma_kernel<<<BATCH * NCHUNK, 64, 0, stream>>>(xBC, Gbuf);
    // 5) per-chunk states (MFMA; overwrites R/u_bf16 aliases — both dead)
    states_mfma_kernel<<<BATCH * NCHUNK * 8, 256, 0, stream>>>(xBC, dtb, Acum, states);
    // 6) inter-chunk scan (4 elems/thread)
    scan_kernel<<<BATCH * NHEADS * 2048 / 256, 256, 0, stream>>>(Acum, states);
    // 7+8) Y = diag + off + D*x  (MFMA, fused)
    y_mfma_kernel<<<BATCH * NCHUNK * NHEADS, 64, 0, stream>>>(
        xBC, dtb, Acum, Gbuf, states, Dv, y);
    // 9) gate + RMSNorm
    gate_norm_kernel<<<ROWS, 256, 0, stream>>>(Z, norm_w, y);
    // 10) out = y @ W_out, full-K pipelined core, fp32 direct (no split-K,
    //     no reduce pass): 32x8 = 256 blocks = 1/CU.
    gemm_out_kernel<<<dim3(ROWS / 256, D_MODEL / 128), 512, 0, stream>>>(
        y, W_outT, out);
}

// Round 2
// 437.446 us; speedup vs baseline: 1.0517x; 1.0175x over previous
//
#include <hip/hip_runtime.h>
#include <hip/hip_bf16.h>
#include <math.h>

#define D_MODEL   1024
#define D_STATE   128
#define HEADDIM   64
#define CHUNK     64
#define D_INNER   2048
#define NHEADS    32
#define D_IN_PROJ 4384   // 2*2048 + 2*128 + 32
#define CONV_CH   2304   // 2048 + 256
#define RCOLS     2336   // CONV_CH + NHEADS (xBC-raw + dt-raw columns)
#define WINT_ROWS 4480   // D_IN_PROJ padded so col-tile 34 stays in-bounds
#define BATCH     2
#define SEQ       4096
#define NCHUNK    64     // SEQ / CHUNK
#define ROWS      (BATCH*SEQ)   // 8192
#define EPS_RMS   1e-5f

typedef __hip_bfloat16 bf16;
typedef __bf16 bf16x8_t __attribute__((ext_vector_type(8)));
typedef float  f32x4_t  __attribute__((ext_vector_type(4)));

__device__ __forceinline__ float siluf_(float x){ return x/(1.f+expf(-x)); }
__device__ __forceinline__ float ldf(const float* p){ return *p; }
__device__ __forceinline__ float ldf(const bf16* p){ return __bfloat162float(*p); }
__device__ __forceinline__ void  stf(float* p, float v){ *p = v; }
__device__ __forceinline__ void  stf(bf16* p, float v){ *p = __float2bfloat16(v); }

__device__ __forceinline__ __bf16 tobf(float v){
    __hip_bfloat16 t = __float2bfloat16(v);
    return *reinterpret_cast<__bf16*>(&t);
}
__device__ __forceinline__ unsigned short bfbits(float v){
    __hip_bfloat16 t = __float2bfloat16(v);
    return *reinterpret_cast<unsigned short*>(&t);
}
__device__ __forceinline__ float bfbits2f(unsigned short u){
    union { unsigned u; float f; } cv; cv.u = ((unsigned)u) << 16; return cv.f;
}

// async global->LDS, 16 B per lane; LDS dest is wave-uniform base + lane*16.
__device__ __forceinline__ void async16(const void* g, void* l) {
    __builtin_amdgcn_global_load_lds(
        (const __attribute__((address_space(1))) unsigned int*)g,
        (__attribute__((address_space(3))) unsigned int*)l, 16, 0, 0);
}

// ---------------------------------------------------------------------------
// Phase-split pipelined MFMA core: 256x128 tile, BK=64, 8 waves (512 thr),
// 3-deep LDS ring (144 KiB), counted s_waitcnt vmcnt(6) at tile top (never 0
// in the main loop), and each K-tile split into 3 phases:
//   {ds_read subtile | stage one chunk of tile t+2 | barrier | setprio(1)+MFMA}
// so the two waves per SIMD stagger ds_read vs MFMA (T3+T4+T5 regime).
// LDS XOR-swizzle (byte ^= (row&7)<<4) with the inverse pre-applied to the
// per-lane GLOBAL source (rule #21); measured conflict-free in round 1.
// Wave (wm=wid>>1, wn=wid&1) owns a 64x64 output patch = 4x4 MFMA frags.
// ---------------------------------------------------------------------------
struct Core {
    f32x4_t acc[4][4];

    __device__ __forceinline__ void stA2(const bf16* __restrict__ A, int lda,
                                         int row0, int kk, __bf16* Asb,
                                         int tid, int lcb, int wb, int c0) {
#pragma unroll
        for (int c = c0; c < c0 + 2; ++c) {
            const char* src = (const char*)(A + (size_t)(row0 + c * 64 + (tid >> 3)) * lda + kk) + lcb;
            async16(src, Asb + c * 4096 + wb);
        }
    }
    __device__ __forceinline__ void stB2(const bf16* __restrict__ Bt, int ldb,
                                         int col0, int kk, __bf16* Bsb,
                                         int tid, int lcb, int wb) {
#pragma unroll
        for (int c = 0; c < 2; ++c) {
            const char* src = (const char*)(Bt + (size_t)(col0 + c * 64 + (tid >> 3)) * ldb + kk) + lcb;
            async16(src, Bsb + c * 4096 + wb);
        }
    }

    __device__ __forceinline__ void run(const bf16* __restrict__ A,
                                        const bf16* __restrict__ Bt,
                                        int lda, int ldb,
                                        int row0, int col0, int k0, int nt,
                                        __bf16* As, __bf16* Bs, int tid) {
        const int wave = tid >> 6, lane = tid & 63;
        const int quad = lane >> 4, l16 = lane & 15;
        const int wm = wave >> 1, wn = wave & 1;
        const int wb  = wave << 9;                       // wave*512 elements
        // inverse-swizzled source column-byte for staging (constant per thread)
        const int lcb = (((tid & 7) ^ ((tid >> 3) & 7)) << 4);
        // read-side swizzle xor (row&7 == l16&7 for all frag reads)
        const int xb = (l16 & 7) << 4;

#pragma unroll
        for (int i = 0; i < 4; ++i)
#pragma unroll
            for (int j = 0; j < 4; ++j) acc[i][j] = (f32x4_t){0.f, 0.f, 0.f, 0.f};

        int aoff[4][2], boff[4][2];
#pragma unroll
        for (int mi = 0; mi < 4; ++mi)
#pragma unroll
            for (int ks = 0; ks < 2; ++ks) {
                const int cb = ((ks << 6) | (quad << 4)) ^ xb;
                aoff[mi][ks] = (wm * 64 + mi * 16 + l16) * 128 + cb;
                boff[mi][ks] = (wn * 64 + mi * 16 + l16) * 128 + cb;
            }

        // prologue: prime tiles 0 and 1 (12 loads/thread, canonical order)
        stA2(A, lda, row0, k0, As, tid, lcb, wb, 0);
        stA2(A, lda, row0, k0, As, tid, lcb, wb, 2);
        stB2(Bt, ldb, col0, k0, Bs, tid, lcb, wb);
        stA2(A, lda, row0, k0 + 64, As + 16384, tid, lcb, wb, 0);
        stA2(A, lda, row0, k0 + 64, As + 16384, tid, lcb, wb, 2);
        stB2(Bt, ldb, col0, k0 + 64, Bs + 8192, tid, lcb, wb);

        const char* AsC = (const char*)As;
        const char* BsC = (const char*)Bs;
        int cur = 0;
        for (int t = 0; t < nt; ++t) {
            // tile t's 6 loads must have landed; tile t+1's 6 may stay in flight
            if (t < nt - 1) asm volatile("s_waitcnt vmcnt(6)" ::: "memory");
            else            asm volatile("s_waitcnt vmcnt(0)" ::: "memory");
            __builtin_amdgcn_s_barrier();
            asm volatile("" ::: "memory");

            const int sb = (cur + 2 >= 3) ? cur - 1 : cur + 2;
            const bool st = (t + 2 < nt);
            const int kk = k0 + (t + 2) * 64;
            const char* Ab = AsC + cur * 32768;
            const char* Bb = BsC + cur * 16384;
            __bf16* Asb = As + sb * 16384;
            __bf16* Bsb = Bs + sb * 8192;

            bf16x8_t af0[2][2], af1[2][2], bf0[2][2], bf1[2][2];

            // ---- phase 0: read a(m0,m1)+b(n0,n1); stage A rows 0..127 (t+2)
#pragma unroll
            for (int i = 0; i < 2; ++i)
#pragma unroll
                for (int ks = 0; ks < 2; ++ks) {
                    af0[i][ks] = *(const bf16x8_t*)(Ab + aoff[i][ks]);
                    bf0[i][ks] = *(const bf16x8_t*)(Bb + boff[i][ks]);
                }
            if (st) stA2(A, lda, row0, kk, Asb, tid, lcb, wb, 0);
            asm volatile("" ::: "memory");
            __builtin_amdgcn_s_barrier();
            asm volatile("" ::: "memory");
            __builtin_amdgcn_s_setprio(1);
#pragma unroll
            for (int ks = 0; ks < 2; ++ks)
#pragma unroll
                for (int mi = 0; mi < 2; ++mi)
#pragma unroll
                    for (int ni = 0; ni < 2; ++ni)
                        acc[mi][ni] = __builtin_amdgcn_mfma_f32_16x16x32_bf16(
                            af0[mi][ks], bf0[ni][ks], acc[mi][ni], 0, 0, 0);
            __builtin_amdgcn_s_setprio(0);

            // ---- phase 1: read b(n2,n3); stage A rows 128..255 (t+2)
#pragma unroll
            for (int i = 0; i < 2; ++i)
#pragma unroll
                for (int ks = 0; ks < 2; ++ks)
                    bf1[i][ks] = *(const bf16x8_t*)(Bb + boff[2 + i][ks]);
            if (st) stA2(A, lda, row0, kk, Asb, tid, lcb, wb, 2);
            asm volatile("" ::: "memory");
            __builtin_amdgcn_s_barrier();
            asm volatile("" ::: "memory");
            __builtin_amdgcn_s_setprio(1);
#pragma unroll
            for (int ks = 0; ks < 2; ++ks)
#pragma unroll
                for (int mi = 0; mi < 2; ++mi)
#pragma unroll
                    for (int ni = 0; ni < 2; ++ni)
                        acc[mi][2 + ni] = __builtin_amdgcn_mfma_f32_16x16x32_bf16(
                            af0[mi][ks], bf1[ni][ks], acc[mi][2 + ni], 0, 0, 0);
            __builtin_amdgcn_s_setprio(0);

            // ---- phase 2: read a(m2,m3); stage B (t+2); compute m23 x n0..3
#pragma unroll
            for (int i = 0; i < 2; ++i)
#pragma unroll
                for (int ks = 0; ks < 2; ++ks)
                    af1[i][ks] = *(const bf16x8_t*)(Ab + aoff[2 + i][ks]);
            if (st) stB2(Bt, ldb, col0, kk, Bsb, tid, lcb, wb);
            asm volatile("" ::: "memory");
            __builtin_amdgcn_s_barrier();
            asm volatile("" ::: "memory");
            __builtin_amdgcn_s_setprio(1);
#pragma unroll
            for (int ks = 0; ks < 2; ++ks)
#pragma unroll
                for (int mi = 0; mi < 2; ++mi) {
#pragma unroll
                    for (int ni = 0; ni < 2; ++ni)
                        acc[2 + mi][2 + ni] = __builtin_amdgcn_mfma_f32_16x16x32_bf16(
                            af1[mi][ks], bf1[ni][ks], acc[2 + mi][2 + ni], 0, 0, 0);
#pragma unroll
                    for (int ni = 0; ni < 2; ++ni)
                        acc[2 + mi][ni] = __builtin_amdgcn_mfma_f32_16x16x32_bf16(
                            af1[mi][ks], bf0[ni][ks], acc[2 + mi][ni], 0, 0, 0);
                }
            __builtin_amdgcn_s_setprio(0);

            cur = (cur + 1 == 3) ? 0 : cur + 1;
        }
    }
};

// Fused Z|R GEMM: grid (32 row-tiles of 256, 35 col-tiles of 128).
__global__ __launch_bounds__(512) void gemm_zr_fused(const bf16* __restrict__ A,
                                                     const bf16* __restrict__ Bt,
                                                     bf16* __restrict__ Z,
                                                     bf16* __restrict__ R) {
    __shared__ __align__(16) __bf16 As[3 * 16384];   // 96 KiB
    __shared__ __align__(16) __bf16 Bs[3 * 8192];    // 48 KiB
    const int tid = threadIdx.x;
    const int row0 = blockIdx.x * 256;
    const int ct   = blockIdx.y;
    Core g;
    g.run(A, Bt, D_MODEL, D_MODEL, row0, ct * 128, 0, 16, As, Bs, tid);

    const int wave = tid >> 6, lane = tid & 63;
    const int quad = lane >> 4, l16 = lane & 15;
    const int wm = wave >> 1, wn = wave & 1;
    bf16* Cp; int ldc_, cl0, ncols;
    if (ct < 16) { Cp = Z; ldc_ = D_INNER; cl0 = ct * 128;           ncols = D_INNER; }
    else         { Cp = R; ldc_ = RCOLS;   cl0 = ct * 128 - D_INNER; ncols = RCOLS; }
#pragma unroll
    for (int ni = 0; ni < 4; ++ni) {
        int gc = cl0 + wn * 64 + ni * 16 + l16;
        if (gc >= ncols) continue;
#pragma unroll
        for (int mi = 0; mi < 4; ++mi)
#pragma unroll
            for (int r = 0; r < 4; ++r) {
                int gr = row0 + wm * 64 + mi * 16 + quad * 4 + r;
                stf(&Cp[(size_t)gr * ldc_ + gc], g.acc[mi][ni][r]);
            }
    }
}

// Out GEMM, full K=2048, fp32 direct to out. grid (32, 8) = 256 blocks (1/CU).
__global__ __launch_bounds__(512) void gemm_out_kernel(const bf16* __restrict__ A,
                                                       const bf16* __restrict__ Bt,
                                                       float* __restrict__ out) {
    __shared__ __align__(16) __bf16 As[3 * 16384];
    __shared__ __align__(16) __bf16 Bs[3 * 8192];
    const int tid = threadIdx.x;
    const int row0 = blockIdx.x * 256;
    const int col0 = blockIdx.y * 128;
    Core g;
    g.run(A, Bt, D_INNER, D_INNER, row0, col0, 0, 32, As, Bs, tid);

    const int wave = tid >> 6, lane = tid & 63;
    const int quad = lane >> 4, l16 = lane & 15;
    const int wm = wave >> 1, wn = wave & 1;
#pragma unroll
    for (int ni = 0; ni < 4; ++ni) {
        int gc = col0 + wn * 64 + ni * 16 + l16;
#pragma unroll
        for (int mi = 0; mi < 4; ++mi)
#pragma unroll
            for (int r = 0; r < 4; ++r) {
                int gr = row0 + wm * 64 + mi * 16 + quad * 4 + r;
                out[(size_t)gr * D_MODEL + gc] = g.acc[mi][ni][r];
            }
    }
}

// fp32 -> bf16 cast, 4 elems/thread
__global__ void cvt_bf16_kernel(const float* __restrict__ src,
                                bf16* __restrict__ dst, int n4) {
    int i = blockIdx.x * 256 + threadIdx.x;
    if (i >= n4) return;
    float4 v = ((const float4*)src)[i];
    dst[i * 4 + 0] = __float2bfloat16(v.x);
    dst[i * 4 + 1] = __float2bfloat16(v.y);
    dst[i * 4 + 2] = __float2bfloat16(v.z);
    dst[i * 4 + 3] = __float2bfloat16(v.w);
}

// Wt[c][r] = W[r][c], fp32 -> bf16.
__global__ __launch_bounds__(256) void transpose_cvt_kernel(const float* __restrict__ W,
                                                            bf16* __restrict__ Wt,
                                                            int R, int C, int Cpad) {
    __shared__ float tile[32][33];
    int c0 = blockIdx.x * 32, r0 = blockIdx.y * 32;
    int tx = threadIdx.x & 31, ty = threadIdx.x >> 5;
    for (int i = ty; i < 32; i += 8) {
        int r = r0 + i, c = c0 + tx;
        tile[i][tx] = (c < C) ? W[(size_t)r * C + c] : 0.f;
    }
    __syncthreads();
    for (int i = ty; i < 32; i += 8) {
        int c = c0 + i, r = r0 + tx;
        stf(&Wt[(size_t)c * R + r], tile[tx][i]);
    }
}

// conv_w[ch][k] fp32  ->  Wc[k][ch] bf16  (coalesced tap-major layout)
__global__ void prep_convw_kernel(const float* __restrict__ conv_w,
                                  bf16* __restrict__ Wc) {
    int i = blockIdx.x * 256 + threadIdx.x;     // CONV_CH*4 = 9216
    if (i >= CONV_CH * 4) return;
    int ch = i >> 2, k = i & 3;
    Wc[k * CONV_CH + ch] = __float2bfloat16(conv_w[ch * 4 + k]);
}

// ---------------------------------------------------------------------------
// Depthwise causal conv (k=4) + bias + SiLU.  One thread = 4 rows x 8 channels.
// ---------------------------------------------------------------------------
__global__ __launch_bounds__(256) void conv_silu_kernel(const bf16* __restrict__ R,
                                                        const bf16* __restrict__ Wc,
                                                        const float* __restrict__ conv_b,
                                                        bf16* __restrict__ xBC) {
    int idx = blockIdx.x * 256 + threadIdx.x;   // ROWS/4 * 288 exactly
    int rq = idx / 288;
    int g = idx - rq * 288;
    int ch0 = g * 8;
    int row0 = rq * 4;
    int l0 = row0 & (SEQ - 1);

    uint4 rv[7];
#pragma unroll
    for (int j = 0; j < 7; ++j) {
        int ls = l0 - 3 + j;
        rv[j] = (ls >= 0) ? *(const uint4*)&R[(size_t)(row0 - 3 + j) * RCOLS + ch0]
                          : make_uint4(0u, 0u, 0u, 0u);
    }
    uint4 wv[4];
#pragma unroll
    for (int k = 0; k < 4; ++k)
        wv[k] = *(const uint4*)&Wc[k * CONV_CH + ch0];
    float4 b0 = ((const float4*)conv_b)[ch0 / 4];
    float4 b1 = ((const float4*)conv_b)[ch0 / 4 + 1];
    const float bias[8] = {b0.x, b0.y, b0.z, b0.w, b1.x, b1.y, b1.z, b1.w};
    float wf[4][8];
#pragma unroll
    for (int k = 0; k < 4; ++k) {
        const unsigned* wp = (const unsigned*)&wv[k];
#pragma unroll
        for (int j2 = 0; j2 < 4; ++j2) {
            wf[k][2 * j2]     = bfbits2f((unsigned short)(wp[j2] & 0xffff));
            wf[k][2 * j2 + 1] = bfbits2f((unsigned short)(wp[j2] >> 16));
        }
    }
#pragma unroll
    for (int j = 0; j < 4; ++j) {
        float acc[8];
#pragma unroll
        for (int cc = 0; cc < 8; ++cc) acc[cc] = bias[cc];
#pragma unroll
        for (int k = 0; k < 4; ++k) {
            const unsigned* vp = (const unsigned*)&rv[j + k];
#pragma unroll
            for (int j2 = 0; j2 < 4; ++j2) {
                unsigned v = vp[j2];
                acc[2 * j2]     += wf[k][2 * j2]     * bfbits2f((unsigned short)(v & 0xffff));
                acc[2 * j2 + 1] += wf[k][2 * j2 + 1] * bfbits2f((unsigned short)(v >> 16));
            }
        }
        unsigned o[4];
#pragma unroll
        for (int j2 = 0; j2 < 4; ++j2)
            o[j2] = (unsigned)bfbits(siluf_(acc[2 * j2])) |
                    ((unsigned)bfbits(siluf_(acc[2 * j2 + 1])) << 16);
        *(uint4*)&xBC[(size_t)(row0 + j) * CONV_CH + ch0] = make_uint4(o[0], o[1], o[2], o[3]);
    }
}

// dt[row][h0..h0+7] = softplus(R[row][CONV_CH+h] + dt_bias[h]), vectorized.
__global__ void dt_kernel(const bf16* __restrict__ R,
                          const float* __restrict__ dt_bias,
                          float* __restrict__ dtb) {
    int i = blockIdx.x * 256 + threadIdx.x;         // ROWS*4 exactly
    int row = i >> 2, h0 = (i & 3) * 8;
    uint4 v = *(const uint4*)&R[(size_t)row * RCOLS + CONV_CH + h0];
    float4 bia0 = ((const float4*)dt_bias)[h0 / 4];
    float4 bia1 = ((const float4*)dt_bias)[h0 / 4 + 1];
    const unsigned vv[4] = {v.x, v.y, v.z, v.w};
    const float bb[8] = {bia0.x, bia0.y, bia0.z, bia0.w, bia1.x, bia1.y, bia1.z, bia1.w};
    float o[8];
#pragma unroll
    for (int j = 0; j < 4; ++j) {
        float a = bfbits2f((unsigned short)(vv[j] & 0xffff)) + bb[2*j];
        float c = bfbits2f((unsigned short)(vv[j] >> 16)) + bb[2*j+1];
        o[2*j]   = (a > 20.f) ? a : log1pf(expf(a));
        o[2*j+1] = (c > 20.f) ? c : log1pf(expf(c));
    }
    float* dp = &dtb[(size_t)row * NHEADS + h0];
    *(float4*)dp       = make_float4(o[0], o[1], o[2], o[3]);
    *(float4*)(dp + 4) = make_float4(o[4], o[5], o[6], o[7]);
}

// Per (b,c,h): inclusive cumsum of A[h]*dt over the 64-long chunk.
__global__ void acum_kernel(const float* __restrict__ dtb,
                            const float* __restrict__ A_log,
                            float* __restrict__ Acum) {
    int bch = blockIdx.x;
    int h = bch & 31;
    int bc = bch >> 5;
    int c = bc & 63, b = bc >> 6;
    int row0 = b * SEQ + c * CHUNK;
    __shared__ float sh[64];
    int l = threadIdx.x;
    float Ah = -expf(A_log[h]);
    sh[l] = Ah * dtb[(size_t)(row0 + l) * NHEADS + h];
    __syncthreads();
    float s = 0.f;
    for (int j = 0; j <= l; ++j) s += sh[j];
    Acum[(size_t)bch * 64 + l] = s;
}

// ---------------------------------------------------------------------------
// MFMA G-chunk: G[l][s] = sum_n C[l,n]*B[s,n].  One wave per (b,c).
// ---------------------------------------------------------------------------
__global__ __launch_bounds__(64) void gchunk_mfma_kernel(const bf16* __restrict__ xBC,
                                                         float* __restrict__ Gbuf) {
    int bc = blockIdx.x;
    int c = bc & 63, b = bc >> 6;
    int row0 = b * SEQ + c * CHUNK;
    int lane = threadIdx.x;
    int quad = lane >> 4, l16 = lane & 15;

    f32x4_t acc[4][4];
#pragma unroll
    for (int i = 0; i < 4; ++i)
#pragma unroll
        for (int j = 0; j < 4; ++j) acc[i][j] = (f32x4_t){0.f, 0.f, 0.f, 0.f};

#pragma unroll
    for (int ks = 0; ks < 4; ++ks) {
        bf16x8_t a[4], bb[4];
#pragma unroll
        for (int mi = 0; mi < 4; ++mi)
            a[mi] = *(const bf16x8_t*)&xBC[(size_t)(row0 + mi * 16 + l16) * CONV_CH +
                                           D_INNER + D_STATE + ks * 32 + quad * 8];
#pragma unroll
        for (int ni = 0; ni < 4; ++ni)
            bb[ni] = *(const bf16x8_t*)&xBC[(size_t)(row0 + ni * 16 + l16) * CONV_CH +
                                            D_INNER + ks * 32 + quad * 8];
#pragma unroll
        for (int mi = 0; mi < 4; ++mi)
#pragma unroll
            for (int ni = 0; ni < 4; ++ni)
                acc[mi][ni] = __builtin_amdgcn_mfma_f32_16x16x32_bf16(
                    a[mi], bb[ni], acc[mi][ni], 0, 0, 0);
    }
#pragma unroll
    for (int ni = 0; ni < 4; ++ni) {
        int s = ni * 16 + l16;
#pragma unroll
        for (int mi = 0; mi < 4; ++mi)
#pragma unroll
            for (int r = 0; r < 4; ++r) {
                int l = mi * 16 + quad * 4 + r;
                Gbuf[(size_t)bc * 4096 + l * 64 + s] = acc[mi][ni][r];
            }
    }
}

// ---------------------------------------------------------------------------
// MFMA chunk-states: S[p][n] = sum_l (x[l,p]*dt[l]*dec[l]) * B[l,n].
// ---------------------------------------------------------------------------
__global__ __launch_bounds__(256) void states_mfma_kernel(const bf16* __restrict__ xBC,
                                                          const float* __restrict__ dtb,
                                                          const float* __restrict__ Acum,
                                                          bf16* __restrict__ states) {
    __shared__ __align__(16) __bf16 BsT[128 * 72];      // [n][l], stride 72 (144 B)
    __shared__ __align__(16) __bf16 xdT[4][64 * 72];    // per-wave [p][l]
    __shared__ float dtdec[4][64];
    int bcq = blockIdx.x;                 // (b*64+c)*8 + hq
    int hq = bcq & 7, bc = bcq >> 3;
    int c = bc & 63, b = bc >> 6;
    int tid = threadIdx.x, wave = tid >> 6, lane = tid & 63;
    int h = hq * 4 + wave;
    int bch = bc * 32 + h;
    int row0 = b * SEQ + c * CHUNK;
    int quad = lane >> 4, l16 = lane & 15;

    {
        float alast = Acum[(size_t)bch * 64 + 63];
        float a = Acum[(size_t)bch * 64 + lane];
        dtdec[wave][lane] = dtb[(size_t)(row0 + lane) * NHEADS + h] * expf(alast - a);
    }
    __syncthreads();
    for (int it = 0; it < 16; ++it) {
        int i2 = tid + 256 * it;
        int l = i2 >> 6;
        int n0 = (i2 & 63) * 2;
        unsigned v = *(const unsigned*)&xBC[(size_t)(row0 + l) * CONV_CH + D_INNER + n0];
        *(unsigned short*)&BsT[(n0    ) * 72 + l] = (unsigned short)(v & 0xffff);
        *(unsigned short*)&BsT[(n0 + 1) * 72 + l] = (unsigned short)(v >> 16);
    }
    for (int it = 0; it < 32; ++it) {
        int l = 2 * it + (lane >> 5);
        int p0 = (lane & 31) * 2;
        unsigned v = *(const unsigned*)&xBC[(size_t)(row0 + l) * CONV_CH + h * 64 + p0];
        float f = dtdec[wave][l];
        xdT[wave][(p0    ) * 72 + l] = tobf(bfbits2f((unsigned short)(v & 0xffff)) * f);
        xdT[wave][(p0 + 1) * 72 + l] = tobf(bfbits2f((unsigned short)(v >> 16)) * f);
    }
    __syncthreads();

    f32x4_t acc[4][8];
#pragma unroll
    for (int i = 0; i < 4; ++i)
#pragma unroll
        for (int j = 0; j < 8; ++j) acc[i][j] = (f32x4_t){0.f, 0.f, 0.f, 0.f};
#pragma unroll
    for (int ks = 0; ks < 2; ++ks) {
        bf16x8_t a[4], bb[8];
#pragma unroll
        for (int mi = 0; mi < 4; ++mi)
            a[mi] = *(const bf16x8_t*)(&xdT[wave][(mi * 16 + l16) * 72 + ks * 32 + quad * 8]);
#pragma unroll
        for (int ni = 0; ni < 8; ++ni)
            bb[ni] = *(const bf16x8_t*)(&BsT[(ni * 16 + l16) * 72 + ks * 32 + quad * 8]);
#pragma unroll
        for (int mi = 0; mi < 4; ++mi)
#pragma unroll
            for (int ni = 0; ni < 8; ++ni)
                acc[mi][ni] = __builtin_amdgcn_mfma_f32_16x16x32_bf16(
                    a[mi], bb[ni], acc[mi][ni], 0, 0, 0);
    }
#pragma unroll
    for (int ni = 0; ni < 8; ++ni) {
        int n = ni * 16 + l16;
#pragma unroll
        for (int mi = 0; mi < 4; ++mi)
#pragma unroll
            for (int r = 0; r < 4; ++r) {
                int p = mi * 16 + quad * 4 + r;
                stf(&states[(size_t)bch * 8192 + p * 128 + n], acc[mi][ni][r]);
            }
    }
}

// Inter-chunk scan (in place), 4 states/thread, fp32 carry.
__global__ void scan_kernel(const float* __restrict__ Acum,
                            bf16* __restrict__ states) {
    int i = blockIdx.x * 256 + threadIdx.x;     // BATCH*NHEADS*2048 exactly
    int pn0 = (i & 2047) * 4;
    int bh = i >> 11;
    int h = bh & 31, b = bh >> 5;
    float carry[4] = {0.f, 0.f, 0.f, 0.f};
    for (int c = 0; c < NCHUNK; ++c) {
        int bch = (b * NCHUNK + c) * NHEADS + h;
        bf16* sp = &states[(size_t)bch * 8192 + pn0];
        uint2 v = *(const uint2*)sp;
        float s0 = bfbits2f((unsigned short)(v.x & 0xffff));
        float s1 = bfbits2f((unsigned short)(v.x >> 16));
        float s2 = bfbits2f((unsigned short)(v.y & 0xffff));
        float s3 = bfbits2f((unsigned short)(v.y >> 16));
        uint2 o;
        o.x = (unsigned)bfbits(carry[0]) | ((unsigned)bfbits(carry[1]) << 16);
        o.y = (unsigned)bfbits(carry[2]) | ((unsigned)bfbits(carry[3]) << 16);
        *(uint2*)sp = o;
        float dec = expf(Acum[(size_t)bch * 64 + 63]);
        carry[0] = carry[0] * dec + s0;
        carry[1] = carry[1] * dec + s1;
        carry[2] = carry[2] * dec + s2;
        carry[3] = carry[3] * dec + s3;
    }
}

// ---------------------------------------------------------------------------
// MFMA Y: Y[l][p] = sum_s M[l][s]*x[s][p] + sum_n (C[l][n]*sdo[l])*state[p][n]
//                  + D[h]*x[l][p].   One wave per (b,c,h).
// ---------------------------------------------------------------------------
__global__ __launch_bounds__(64) void y_mfma_kernel(const bf16* __restrict__ xBC,
                                                    const float* __restrict__ dtb,
                                                    const float* __restrict__ Acum,
                                                    const float* __restrict__ Gbuf,
                                                    const bf16* __restrict__ states,
                                                    const float* __restrict__ Dv,
                                                    bf16* __restrict__ y) {
    __shared__ __align__(16) __bf16 Mm[64 * 72];
    __shared__ __align__(16) __bf16 xsT[64 * 72];
    __shared__ float acs[64], dtss[64], sdos[64];
    int bch = blockIdx.x;
    int h = bch & 31, bc = bch >> 5;
    int c = bc & 63, b = bc >> 6;
    int row0 = b * SEQ + c * CHUNK;
    int lane = threadIdx.x;
    int quad = lane >> 4, l16 = lane & 15;

    {
        float a = Acum[(size_t)bch * 64 + lane];
        acs[lane] = a;
        sdos[lane] = expf(a);
        dtss[lane] = dtb[(size_t)(row0 + lane) * NHEADS + h];
    }
    __syncthreads();
    for (int l = 0; l < 64; ++l) {
        int s = lane;
        float d = acs[l] - acs[s];
        float g = (s <= l) ? Gbuf[(size_t)bc * 4096 + l * 64 + s] * dtss[s] : 0.f;
        float coef = g * expf((s <= l) ? d : 0.f);
        Mm[l * 72 + s] = tobf(coef);
    }
    for (int it = 0; it < 32; ++it) {
        int l = 2 * it + (lane >> 5);
        int p0 = (lane & 31) * 2;
        unsigned v = *(const unsigned*)&xBC[(size_t)(row0 + l) * CONV_CH + h * 64 + p0];
        *(unsigned short*)&xsT[(p0    ) * 72 + l] = (unsigned short)(v & 0xffff);
        *(unsigned short*)&xsT[(p0 + 1) * 72 + l] = (unsigned short)(v >> 16);
    }
    __syncthreads();

    f32x4_t acc[4][4];
#pragma unroll
    for (int i = 0; i < 4; ++i)
#pragma unroll
        for (int j = 0; j < 4; ++j) acc[i][j] = (f32x4_t){0.f, 0.f, 0.f, 0.f};

#pragma unroll
    for (int ks = 0; ks < 2; ++ks) {
        bf16x8_t a[4], bb[4];
#pragma unroll
        for (int mi = 0; mi < 4; ++mi)
            a[mi] = *(const bf16x8_t*)(&Mm[(mi * 16 + l16) * 72 + ks * 32 + quad * 8]);
#pragma unroll
        for (int ni = 0; ni < 4; ++ni)
            bb[ni] = *(const bf16x8_t*)(&xsT[(ni * 16 + l16) * 72 + ks * 32 + quad * 8]);
#pragma unroll
        for (int mi = 0; mi < 4; ++mi)
#pragma unroll
            for (int ni = 0; ni < 4; ++ni)
                acc[mi][ni] = __builtin_amdgcn_mfma_f32_16x16x32_bf16(
                    a[mi], bb[ni], acc[mi][ni], 0, 0, 0);
    }
    float sdo_mi[4];
#pragma unroll
    for (int mi = 0; mi < 4; ++mi) sdo_mi[mi] = sdos[mi * 16 + l16];
#pragma unroll
    for (int ks = 0; ks < 4; ++ks) {
        bf16x8_t a[4], bb[4];
#pragma unroll
        for (int mi = 0; mi < 4; ++mi) {
            const unsigned* cp = (const unsigned*)&xBC[(size_t)(row0 + mi * 16 + l16) * CONV_CH
                                                       + D_INNER + D_STATE + ks * 32 + quad * 8];
            float sc = sdo_mi[mi];
#pragma unroll
            for (int jj = 0; jj < 4; ++jj) {
                unsigned v = cp[jj];
                a[mi][2 * jj    ] = tobf(bfbits2f((unsigned short)(v & 0xffff)) * sc);
                a[mi][2 * jj + 1] = tobf(bfbits2f((unsigned short)(v >> 16)) * sc);
            }
        }
#pragma unroll
        for (int ni = 0; ni < 4; ++ni)
            bb[ni] = *(const bf16x8_t*)&states[(size_t)bch * 8192 + (ni * 16 + l16) * 128
                                               + ks * 32 + quad * 8];
#pragma unroll
        for (int mi = 0; mi < 4; ++mi)
#pragma unroll
            for (int ni = 0; ni < 4; ++ni)
                acc[mi][ni] = __builtin_amdgcn_mfma_f32_16x16x32_bf16(
                    a[mi], bb[ni], acc[mi][ni], 0, 0, 0);
    }
    float Dh = Dv[h];
#pragma unroll
    for (int ni = 0; ni < 4; ++ni) {
        int p = ni * 16 + l16;
#pragma unroll
        for (int mi = 0; mi < 4; ++mi)
#pragma unroll
            for (int r = 0; r < 4; ++r) {
                int l = mi * 16 + quad * 4 + r;
                float xv = bfbits2f(*(const unsigned short*)&xsT[p * 72 + l]);
                stf(&y[(size_t)(row0 + l) * D_INNER + h * 64 + p],
                    acc[mi][ni][r] + Dh * xv);
            }
    }
}

// Per row: v = y * silu(z); y = v * rsqrt(mean(v^2)+eps) * norm_w.
__global__ __launch_bounds__(256) void gate_norm_kernel(const bf16* __restrict__ Z,
                                                        const float* __restrict__ nw,
                                                        bf16* __restrict__ y) {
    int row = blockIdx.x;
    int tid = threadIdx.x;
    int col0 = tid * 8;
    uint4 zv = *(const uint4*)&Z[(size_t)row * D_INNER + col0];
    uint4 yv = *(const uint4*)&y[(size_t)row * D_INNER + col0];
    const unsigned zz[4] = {zv.x, zv.y, zv.z, zv.w};
    const unsigned yy[4] = {yv.x, yv.y, yv.z, yv.w};
    float vals[8];
    float local = 0.f;
#pragma unroll
    for (int j = 0; j < 4; ++j) {
        float z0 = bfbits2f((unsigned short)(zz[j] & 0xffff));
        float z1 = bfbits2f((unsigned short)(zz[j] >> 16));
        float y0 = bfbits2f((unsigned short)(yy[j] & 0xffff));
        float y1 = bfbits2f((unsigned short)(yy[j] >> 16));
        float v0 = y0 * siluf_(z0);
        float v1 = y1 * siluf_(z1);
        vals[2*j] = v0; vals[2*j+1] = v1;
        local += v0 * v0 + v1 * v1;
    }
#pragma unroll
    for (int off = 32; off; off >>= 1) local += __shfl_down(local, off, 64);
    __shared__ float wsum[4];
    if ((tid & 63) == 0) wsum[tid >> 6] = local;
    __syncthreads();
    float total = wsum[0] + wsum[1] + wsum[2] + wsum[3];
    float scale = rsqrtf(total / (float)D_INNER + EPS_RMS);
    float4 w0 = ((const float4*)nw)[col0 / 4];
    float4 w1 = ((const float4*)nw)[col0 / 4 + 1];
    const float ww[8] = {w0.x, w0.y, w0.z, w0.w, w1.x, w1.y, w1.z, w1.w};
    unsigned o[4];
#pragma unroll
    for (int j = 0; j < 4; ++j)
        o[j] = (unsigned)bfbits(vals[2*j] * scale * ww[2*j]) |
               ((unsigned)bfbits(vals[2*j+1] * scale * ww[2*j+1]) << 16);
    *(uint4*)&y[(size_t)row * D_INNER + col0] = make_uint4(o[0], o[1], o[2], o[3]);
}

// ---------------------------------------------------------------------------
extern "C" void kernel_launch(void* const* d_in, const int* in_sizes, int n_in,
                              void* d_out, int out_size, void* d_ws, size_t ws_size,
                              hipStream_t stream) {
    const float* u       = (const float*)d_in[0];
    const float* W_in    = (const float*)d_in[1];
    const float* conv_w  = (const float*)d_in[2];
    const float* conv_b  = (const float*)d_in[3];
    const float* dt_bias = (const float*)d_in[4];
    const float* A_log   = (const float*)d_in[5];
    const float* Dv      = (const float*)d_in[6];
    const float* norm_w  = (const float*)d_in[7];
    const float* W_out   = (const float*)d_in[8];
    float* out = (float*)d_out;

    const size_t sz_xBC    = (size_t)ROWS * CONV_CH * 2;
    const size_t sz_Z      = (size_t)ROWS * D_INNER * 2;
    const size_t sz_y      = (size_t)ROWS * D_INNER * 2;
    const size_t sz_states = (size_t)BATCH * NCHUNK * NHEADS * 8192 * 2;  // 67.1 MB
    const size_t sz_dtb    = (size_t)ROWS * NHEADS * 4;
    const size_t sz_Acum   = (size_t)BATCH * NCHUNK * NHEADS * 64 * 4;
    const size_t sz_Gbuf   = (size_t)BATCH * NCHUNK * 4096 * 4;
    const size_t sz_WinT   = (size_t)WINT_ROWS * D_MODEL * 2;
    const size_t sz_WoutT  = (size_t)D_MODEL * D_INNER * 2;
    const size_t sz_Wc     = (size_t)CONV_CH * 4 * 2;
    const size_t need = sz_xBC + sz_Z + sz_y + sz_states + sz_dtb + sz_Acum +
                        sz_Gbuf + sz_WinT + sz_WoutT + sz_Wc;
    if (ws_size < need) {
        hipMemsetAsync(d_out, 0, (size_t)out_size * sizeof(float), stream);
        return;
    }
    char* ws = (char*)d_ws;
    size_t off = 0;
    bf16*  xBC    = (bf16*) (ws + off); off += sz_xBC;
    bf16*  Z      = (bf16*) (ws + off); off += sz_Z;
    bf16*  y      = (bf16*) (ws + off); off += sz_y;
    bf16*  states = (bf16*) (ws + off); off += sz_states;
    float* dtb    = (float*)(ws + off); off += sz_dtb;
    float* Acum   = (float*)(ws + off); off += sz_Acum;
    float* Gbuf   = (float*)(ws + off); off += sz_Gbuf;
    bf16*  W_inT  = (bf16*) (ws + off); off += sz_WinT;
    bf16*  W_outT = (bf16*) (ws + off); off += sz_WoutT;
    bf16*  Wc     = (bf16*) (ws + off); off += sz_Wc;
    // Aliases of the states region (67.1 MB), dead before their overwrite:
    //  - R (38.3 MB) + u_bf16 (16.8 MB): dead before states_mfma_kernel.
    bf16*  R        = states;
    bf16*  u_bf16   = (bf16*)((char*)states + (size_t)ROWS * RCOLS * 2);

    // 0) prep
    cvt_bf16_kernel<<<(ROWS * D_MODEL / 4 + 255) / 256, 256, 0, stream>>>(
        u, u_bf16, ROWS * D_MODEL / 4);
    transpose_cvt_kernel<<<dim3(WINT_ROWS / 32, D_MODEL / 32), 256, 0, stream>>>(
        W_in, W_inT, D_MODEL, D_IN_PROJ, WINT_ROWS);
    transpose_cvt_kernel<<<dim3(D_MODEL / 32, D_INNER / 32), 256, 0, stream>>>(
        W_out, W_outT, D_INNER, D_MODEL, D_MODEL);
    prep_convw_kernel<<<(CONV_CH * 4 + 255) / 256, 256, 0, stream>>>(conv_w, Wc);
    // 1) fused Z|R GEMM: phase-split pipelined 256x128 core, 32x35 blocks
    gemm_zr_fused<<<dim3(ROWS / 256, 35), 512, 0, stream>>>(u_bf16, W_inT, Z, R);
    // 2) conv + silu (4 rows/thread) ; dt
    conv_silu_kernel<<<ROWS / 4 * 288 / 256, 256, 0, stream>>>(R, Wc, conv_b, xBC);
    dt_kernel<<<ROWS * 4 / 256, 256, 0, stream>>>(R, dt_bias, dtb);
    // 3) per-chunk cumsum of A*dt
    acum_kernel<<<BATCH * NCHUNK * NHEADS, 64, 0, stream>>>(dtb, A_log, Acum);
    // 4) G = C @ B^T per (b,c)  (MFMA)
    gchunk_mfma_kernel<<<BATCH * NCHUNK, 64, 0, stream>>>(xBC, Gbuf);
    // 5) per-chunk states (MFMA; overwrites R/u_bf16 aliases — both dead)
    states_mfma_kernel<<<BATCH * NCHUNK * 8, 256, 0, stream>>>(xBC, dtb, Acum, states);
    // 6) inter-chunk scan (4 elems/thread)
    scan_kernel<<<BATCH * NHEADS * 2048 / 256, 256, 0, stream>>>(Acum, states);
    // 7+8) Y = diag + off + D*x  (MFMA, fused)
    y_mfma_kernel<<<BATCH * NCHUNK * NHEADS, 64, 0, stream>>>(
        xBC, dtb, Acum, Gbuf, states, Dv, y);
    // 9) gate + RMSNorm
    gate_norm_kernel<<<ROWS, 256, 0, stream>>>(Z, norm_w, y);
    // 10) out = y @ W_out, full-K phase-split core, fp32 direct: 256 blocks.
    gemm_out_kernel<<<dim3(ROWS / 256, D_MODEL / 128), 512, 0, stream>>>(
        y, W_outT, out);
}